// Round 11
// baseline (575.898 us; speedup 1.0000x reference)
//
#include <hip/hip_runtime.h>
#include <math.h>

#define BATCH 32
#define NN 1024
#define MM 1024
#define LPATH (NN + MM - 1)     // 2047

// ---------------- R11: 4-row-per-lane panel geometry ----------------
// Panel = 256 rows x 128 cols; 1 wave; lane owns rows 4l..4l+3; 1 col/step
// (4 cells/step, the proven legacy RRL=4 column chain). Grid: 4 bands x 8
// chunks per batch -> 11 diagonal launches (vs 15 with 128-row panels).
// Boundaries via ws planes between launches (proven R5 handshake, no fences).
#define PQ 128                  // panel cols
#define PBR 256                 // panel rows
#define GB 4                    // bands
#define GH 8                    // chunk cols
#define PAN_WORDS 3072          // 48 words x 64 lanes (8 bits/step, 192 steps)
#define BAT_WORDS (GB * GH * PAN_WORDS)               // 98304 words / batch
#define RCPL (9 * 1024)
#define RC_OFFW ((size_t)BATCH * BAT_WORDS)
#define BR_OFFW (RC_OFFW + (size_t)BATCH * RCPL)
#define WS_WORDS (BR_OFFW + (size_t)BATCH * RCPL)
#define REQ_WS_NEW (WS_WORDS * 4)                     // ~14.3 MB

// Legacy (proven 557us) path requirement
#define DEC_WORDS_PER_BATCH ((NN / 4) * (MM / 4))     // 65536
#define REQ_WS ((size_t)BATCH * DEC_WORDS_PER_BATCH * 4)   // 8 MB

__global__ void init_kernel(float* out) { out[0] = 0.0f; }

// ---- init (R5 verbatim): INF boundary planes (c=0 / r=0) + out=0 -----------
__global__ void init2(float* __restrict__ ws, float* __restrict__ out)
{
    const int b = blockIdx.x, t = threadIdx.x;
    const float INF = __builtin_inff();
    if (b == 0 && t == 0) out[0] = 0.0f;
    float* rc0 = ws + RC_OFFW + (size_t)b * RCPL;     // rcol[b][0][*]
    float* br0 = ws + BR_OFFW + (size_t)b * RCPL;     // brow[b][0][*]
    for (int i = t; i < 1024; i += 256) { rc0[i] = INF; br0[i] = INF; }
}

__device__ __forceinline__ float wave_shr1(float v)
{
    return __int_as_float(__builtin_amdgcn_update_dpp(
        __float_as_int(v), __float_as_int(v), 0x138, 0xF, 0xF, false));
}

// ---- Panel DP: 256-row x 128-col panels, launch per grid anti-diagonal ------
// Per-column 4-row chain is the legacy RRL=4 pattern verbatim (absmax=0
// proven in R0/R2): dg<-lf, up<-D propagation, argmin tie order [dg,up,lf].
// Decision word: 4 steps x 8 bits; bit (s&3)*8 + row*2.
__global__ __launch_bounds__(64, 1) void dtw_panel4(
    const float* __restrict__ preds, const float* __restrict__ targs,
    float* __restrict__ ws, const int diag)
{
    const int b = blockIdx.y;
    const int r0 = (diag > GH - 1) ? diag - (GH - 1) : 0;
    const int r = r0 + blockIdx.x;          // band in [0,4)
    const int c = diag - r;                 // chunk col in [0,8)
    const int l = threadIdx.x;
    const float INF = __builtin_inff();

    __shared__ __align__(16) float txP[260], tyP[260];   // padded col streams
    __shared__ __align__(16) float TL[200];              // top row stream
    __shared__ __align__(16) float botL[128];            // bottom row collect

    // pads (reads for inactive jq land here; values unused)
    if (l < 63) { txP[l] = 0.f; tyP[l] = 0.f; }
    txP[191 + l] = 0.f; tyP[191 + l] = 0.f;
    if (l < 6) { txP[255 + l] = 0.f; tyP[255 + l] = 0.f; }
    TL[128 + l] = INF; if (l < 8) TL[192 + l] = INF;

    // stage targ cols [128c .. 128c+127]
    const float4* tg4 = (const float4*)targs + (size_t)b * MM + c * PQ;
    {
        const float4 a = tg4[l], e = tg4[64 + l];
        txP[63 + l] = a.x;      tyP[63 + l] = a.y;
        txP[63 + 64 + l] = e.x; tyP[63 + 64 + l] = e.y;
    }
    // top boundary row (brow[b][r] = D of global row 256r-1; r=0 -> INF)
    const float* browR = ws + BR_OFFW + ((size_t)b * 9 + r) * 1024 + c * PQ;
    TL[l] = browR[l]; TL[64 + l] = browR[64 + l];

    // pred rows 4l..4l+3
    const float4* pp4 = (const float4*)preds + (size_t)b * NN + r * PBR;
    const float4 p0 = pp4[4 * l],     p1 = pp4[4 * l + 1];
    const float4 p2 = pp4[4 * l + 2], p3 = pp4[4 * l + 3];
    const float px0 = p0.x, py0 = p0.y, px1 = p1.x, py1 = p1.y;
    const float px2 = p2.x, py2 = p2.y, px3 = p3.x, py3 = p3.y;

    // left boundary (rcol[b][c] = D of global col 128c-1; c=0 -> INF)
    const float* rc = ws + RC_OFFW + ((size_t)b * 9 + c) * 1024 + r * PBR;
    float D0 = rc[4 * l], D1 = rc[4 * l + 1];
    float D2 = rc[4 * l + 2], D3 = rc[4 * l + 3];
    const float corner = (c == 0) ? ((r == 0) ? 0.0f : INF) : browR[-1];
    const float dg0init = (l == 0) ? corner : rc[4 * l - 1];

    unsigned* __restrict__ decP = (unsigned*)ws + (size_t)b * BAT_WORDS
                                + (size_t)(r * GH + c) * PAN_WORDS + l;
    __syncthreads();

    // 8-slot register ring for tx/ty, prefetch distance 4 steps (R5 verbatim)
    float txb[8], tyb[8];
    #pragma unroll
    for (int k = 0; k < 4; ++k) { txb[k] = txP[63 + k - l]; tyb[k] = tyP[63 + k - l]; }
    float up0prev = INF;

    for (int it = 0; it < 24; ++it) {
        const int s0 = it * 8;
        const float4 T4a = *(const float4*)&TL[s0];
        const float4 T4b = *(const float4*)&TL[s0 + 4];
        const float Tv[8] = {T4a.x, T4a.y, T4a.z, T4a.w,
                             T4b.x, T4b.y, T4b.z, T4b.w};
        unsigned w0 = 0, w1 = 0;
        #pragma unroll
        for (int k = 0; k < 8; ++k) {
            const int s = s0 + k;
            const int jq = s - l;
            txb[(k + 4) & 7] = txP[63 + jq + 4];
            tyb[(k + 4) & 7] = tyP[63 + jq + 4];
            const float sh = wave_shr1(D3);       // lane l-1's row 4l-1 @ jq
            const float up0 = (l == 0) ? Tv[k] : sh;
            const float tx = txb[k], ty = tyb[k];
            float dg = (jq == 0) ? dg0init : up0prev;
            float up = up0;
            unsigned mb = 0;
            // row 0 (legacy chain: lf = D0)
            {
                const float dx = px0 - tx, dy = py0 - ty;
                const float cc = __builtin_amdgcn_sqrtf(dx * dx + dy * dy);
                const float mn = fminf(dg, fminf(up, D0));
                const float Dn = cc + mn;
                mb |= ((mn == dg) ? 0u : ((mn == up) ? 1u : 2u)) << 0;
                dg = D0; up = Dn; D0 = (jq >= 0 && jq < PQ) ? Dn : D0;
                // NOTE: commit handled uniformly below via act; use temp:
                // (we re-commit below, so stash Dn in D0 only if act)
                // -- implemented via act at end; keep chain values:
                if (!(jq >= 0 && jq < PQ)) { /* chain uses old values */ }
                (void)0;
                // chain correctness: dg/up must use PRE-commit values; since
                // dg was captured before commit and up = Dn (new), matching
                // the legacy chain exactly. D0 commit gated by act above.
            }
            // row 1
            {
                const float dx = px1 - tx, dy = py1 - ty;
                const float cc = __builtin_amdgcn_sqrtf(dx * dx + dy * dy);
                const float mn = fminf(dg, fminf(up, D1));
                const float Dn = cc + mn;
                mb |= ((mn == dg) ? 0u : ((mn == up) ? 1u : 2u)) << 2;
                dg = D1; up = Dn; D1 = (jq >= 0 && jq < PQ) ? Dn : D1;
            }
            // row 2
            {
                const float dx = px2 - tx, dy = py2 - ty;
                const float cc = __builtin_amdgcn_sqrtf(dx * dx + dy * dy);
                const float mn = fminf(dg, fminf(up, D2));
                const float Dn = cc + mn;
                mb |= ((mn == dg) ? 0u : ((mn == up) ? 1u : 2u)) << 4;
                dg = D2; up = Dn; D2 = (jq >= 0 && jq < PQ) ? Dn : D2;
            }
            // row 3
            {
                const float dx = px3 - tx, dy = py3 - ty;
                const float cc = __builtin_amdgcn_sqrtf(dx * dx + dy * dy);
                const float mn = fminf(dg, fminf(up, D3));
                const float Dn = cc + mn;
                mb |= ((mn == dg) ? 0u : ((mn == up) ? 1u : 2u)) << 6;
                const bool act = (jq >= 0) && (jq < PQ);
                if (act) { D3 = Dn; if (l == 63) botL[jq] = Dn; }
            }
            up0prev = up0;
            if (k < 4) w0 |= mb << (8 * (s & 3));
            else       w1 |= mb << (8 * (s & 3));
        }
        decP[(2 * it) * 64] = w0;               // coalesced 256B stores
        decP[(2 * it + 1) * 64] = w1;
    }

    // publish right column (D regs frozen at jq=127 by predication)
    float* rcw = ws + RC_OFFW + ((size_t)b * 9 + (c + 1)) * 1024 + r * PBR;
    rcw[4 * l] = D0; rcw[4 * l + 1] = D1;
    rcw[4 * l + 2] = D2; rcw[4 * l + 3] = D3;
    __syncthreads();
    if (r < GB - 1) {
        float* brw = ws + BR_OFFW + ((size_t)b * 9 + (r + 1)) * 1024 + c * PQ;
        brw[l] = botL[l]; brw[64 + l] = botL[64 + l];
    }
}

// ---- Backtrack + loss: 32 blocks x 256 threads (R5-proven global walk) ------
// Word for cell (i,j): band pr=i>>8, chunk pc=j>>7, lane ll=(i&255)>>2,
// step s=(j&127)+ll; widx=(pr*8+pc)*3072+(s>>2)*64+ll; bit=(s&3)*8+(i&3)*2.
__global__ __launch_bounds__(256, 1) void dtw_bt(
    const float* __restrict__ preds, const float* __restrict__ targs,
    const float* __restrict__ subcoef, const unsigned* __restrict__ wsu,
    float* __restrict__ out)
{
    const int b = blockIdx.x, t = threadIdx.x;
    __shared__ float pxA[NN], pyA[NN], txA[MM], tyA[MM];   // 16 KB
    __shared__ unsigned path[2048];                        // 8 KB
    __shared__ int sN;
    __shared__ float wsum[4];

    for (int it = 0; it < 4; ++it) {
        const int idx = it * 256 + t;
        const float4 p4 = ((const float4*)preds)[(size_t)b * NN + idx];
        pxA[idx] = p4.x; pyA[idx] = p4.y;
        const float4 t4 = ((const float4*)targs)[(size_t)b * MM + idx];
        txA[idx] = t4.x; tyA[idx] = t4.y;
    }
    __syncthreads();

    if (t == 0) {
        const unsigned* __restrict__ decB = wsu + (size_t)b * BAT_WORDS;
        int i = NN - 1, j = MM - 1, n = 0;
        int cwidx = -1; unsigned cw = 0;
        while (true) {
            path[n++] = ((unsigned)i << 16) | (unsigned)j;
            if ((i | j) == 0) break;
            const int ll = (i & 255) >> 2;
            const int s = (j & 127) + ll;
            const int widx = (((i >> 8) << 3) + (j >> 7)) * PAN_WORDS
                           + (s >> 2) * 64 + ll;
            if (widx != cwidx) { cw = decB[widx]; cwidx = widx; }
            const unsigned m = (cw >> ((s & 3) * 8 + (i & 3) * 2)) & 3u;
            i -= (m != 2u); j -= (m != 1u);
        }
        sN = n;
    }
    __syncthreads();

    const float sc0 = subcoef[0], sc1 = subcoef[1];
    const int n = sN;
    float acc = 0.0f;
    for (int p = t; p < n; p += 256) {
        const unsigned e = path[p];
        const int i = (int)(e >> 16), j = (int)(e & 0xffffu);
        acc += fabsf(pxA[i] - txA[j]) * sc0 + fabsf(pyA[i] - tyA[j]) * sc1;
    }
    #pragma unroll
    for (int o = 32; o > 0; o >>= 1) acc += __shfl_down(acc, o);
    if ((t & 63) == 0) wsum[t >> 6] = acc;
    __syncthreads();
    if (t == 0) atomicAdd(out, (wsum[0] + wsum[1]) + (wsum[2] + wsum[3]));
}

// =================== Legacy proven path (557us, needs 8MB) ===================
__device__ inline void bt_walk4(const unsigned* __restrict__ sdec, int roff,
                                int iLow, int& i, int& j, int& n,
                                unsigned* __restrict__ path)
{
    int ri = i >> 2, jc = j >> 2;
    unsigned w = sdec[(ri - roff) * 256 + jc];
    while (true) {
        const int base = (ri - roff) * 256 + jc;
        const unsigned wl = sdec[(jc > 0)    ? base - 1   : base];
        const unsigned wu = sdec[(ri > roff) ? base - 256 : base];
        const unsigned wd = sdec[(ri > roff && jc > 0) ? base - 257 : base];
        bool done = false, susp = false;
        while (true) {
            path[n++] = ((unsigned)i << 16) | (unsigned)j;
            if ((i | j) == 0) { done = true; break; }
            const unsigned m = (w >> (((i & 3) * 4 + (j & 3)) * 2)) & 3u;
            i -= (m != 2u); j -= (m != 1u);
            if (i < iLow) { susp = true; break; }
            if ((i >> 2) != ri || (j >> 2) != jc) break;
        }
        if (done || susp) break;
        const int nri = i >> 2, njc = j >> 2;
        w = (nri == ri) ? wl : ((njc == jc) ? wu : wd);
        ri = nri; jc = njc;
    }
}

#define RRL 4
#define CCL 4
#define LANES 64
#define NWAVE 4
#define TPBL (MM / 4)
#define NSUP (TPBL + LANES - 1)
#define LAG 72
#define TOTL (NSUP + (NWAVE - 1) * LAG)
#define DEPTH 32

__global__ __launch_bounds__(256, 1) void dtw_fused_legacy(
    const float* __restrict__ preds, const float* __restrict__ targs,
    const float* __restrict__ subcoef, unsigned* __restrict__ dec,
    float* __restrict__ out)
{
    const int b = blockIdx.x, t = threadIdx.x;
    const int l = t & 63, w = t >> 6;
    const float INF = __builtin_inff();

    __shared__ float pxA[NN], pyA[NN], txA[MM], tyA[MM];
    __shared__ float4 ring[NWAVE - 1][DEPTH];
    __shared__ unsigned sdec[128 * 256];
    __shared__ unsigned path[LPATH + 1];
    __shared__ int sI, sJ, sN;
    __shared__ float wsum[NWAVE];

    for (int it = 0; it < NN / 256; ++it) {
        const int idx = it * 256 + t;
        const float4 p4 = ((const float4*)preds)[(size_t)b * NN + idx];
        pxA[idx] = p4.x; pyA[idx] = p4.y;
        const float4 t4 = ((const float4*)targs)[(size_t)b * MM + idx];
        txA[idx] = t4.x; tyA[idx] = t4.y;
    }
    __syncthreads();

    const int i0 = (w << 8) + (l << 2);
    const float4 px4 = ((const float4*)pxA)[i0 >> 2];
    const float4 py4 = ((const float4*)pyA)[i0 >> 2];
    const float px[RRL] = {px4.x, px4.y, px4.z, px4.w};
    const float py[RRL] = {py4.x, py4.y, py4.z, py4.w};
    unsigned* __restrict__ decW =
        dec + (size_t)b * DEC_WORDS_PER_BATCH + ((size_t)w << 14) + (size_t)l;

    float Dp[RRL], Dbot[CCL], bv[CCL];
    #pragma unroll
    for (int r = 0; r < RRL; ++r) Dp[r] = INF;
    #pragma unroll
    for (int c = 0; c < CCL; ++c) { Dbot[c] = INF; bv[c] = INF; }
    float bndRet = (w == 0 && l == 0) ? 0.0f : INF;
    float4 gcur = make_float4(INF, INF, INF, INF);
    float4 tx4 = ((const float4*)txA)[0], ty4 = ((const float4*)tyA)[0];
    const float4* __restrict__ ringR = ring[(w > 0) ? (w - 1) : 0];

    for (int u = 0; u < TOTL; ++u) {
        const int ul = u - LAG * w;
        if (l == 0) {
            const bool gb = (w > 0) && (ul >= 0) && (ul < TPBL);
            bv[0] = gb ? gcur.x : INF; bv[1] = gb ? gcur.y : INF;
            bv[2] = gb ? gcur.z : INF; bv[3] = gb ? gcur.w : INF;
        }
        const bool act = (ul >= l) && (ul < l + TPBL);
        if (act) {
            const float cx[CCL] = {tx4.x, tx4.y, tx4.z, tx4.w};
            const float cy[CCL] = {ty4.x, ty4.y, ty4.z, ty4.w};
            float cost[RRL][CCL];
            #pragma unroll
            for (int c = 0; c < CCL; ++c)
                #pragma unroll
                for (int r = 0; r < RRL; ++r) {
                    const float dx = px[r] - cx[c], dy = py[r] - cy[c];
                    cost[r][c] = __builtin_amdgcn_sqrtf(dx * dx + dy * dy);
                }
            unsigned word = 0;
            #pragma unroll
            for (int c = 0; c < CCL; ++c) {
                float up = bv[c];
                float dg = (c == 0) ? bndRet : bv[c - 1];
                #pragma unroll
                for (int r = 0; r < RRL; ++r) {
                    const float lf = Dp[r];
                    const unsigned m = (dg <= up && dg <= lf) ? 0u
                                     : ((up <= lf) ? 1u : 2u);
                    const float D = cost[r][c] + fminf(dg, fminf(up, lf));
                    word |= m << ((r * 4 + c) * 2);
                    dg = lf; up = D; Dp[r] = D;
                }
                Dbot[c] = up;
            }
            decW[(ul & 255) << 6] = word;
            if (l == LANES - 1 && w < NWAVE - 1)
                ring[w][ul & (DEPTH - 1)] =
                    make_float4(Dbot[0], Dbot[1], Dbot[2], Dbot[3]);
        }
        bndRet = bv[CCL - 1];
        #pragma unroll
        for (int c = 0; c < CCL; ++c) bv[c] = __shfl_up(Dbot[c], 1);
        const int un = ul + 1;
        if (un >= l && un < l + TPBL) {
            const int jn = CCL * (un - l);
            tx4 = ((const float4*)txA)[jn >> 2];
            ty4 = ((const float4*)tyA)[jn >> 2];
        }
        if (w > 0 && un >= 0 && un < TPBL)
            gcur = ringR[(un + 63) & (DEPTH - 1)];
        if ((u & 7) == 7) __syncthreads();
    }

    __threadfence_block();
    __syncthreads();

    const unsigned* __restrict__ decB = dec + (size_t)b * DEC_WORDS_PER_BATCH;
    {
        const uint4* g4 = (const uint4*)(decB + 32768);
        for (int k = t; k < 8192; k += 256) {
            const uint4 v = g4[k];
            const int kb = k << 2;
            const int wv = kb >> 14;
            const int rem = kb & 16383;
            const int q = rem >> 6;
            const int lb = rem & 63;
            const unsigned wd[4] = {v.x, v.y, v.z, v.w};
            #pragma unroll
            for (int e = 0; e < 4; ++e) {
                const int ll = lb + e;
                const int row = (wv << 6) + ll;
                const int jc = (q - ll) & 255;
                sdec[(row << 8) + jc] = wd[e];
            }
        }
    }
    __syncthreads();
    if (t == 0) {
        int i = NN - 1, j = MM - 1, n = 0;
        bt_walk4(sdec, 128, 512, i, j, n, path);
        sI = i; sJ = j; sN = n;
    }
    __syncthreads();
    {
        const uint4* g4 = (const uint4*)decB;
        for (int k = t; k < 8192; k += 256) {
            const uint4 v = g4[k];
            const int kb = k << 2;
            const int wv = kb >> 14;
            const int rem = kb & 16383;
            const int q = rem >> 6;
            const int lb = rem & 63;
            const unsigned wd[4] = {v.x, v.y, v.z, v.w};
            #pragma unroll
            for (int e = 0; e < 4; ++e) {
                const int ll = lb + e;
                const int row = (wv << 6) + ll;
                const int jc = (q - ll) & 255;
                sdec[(row << 8) + jc] = wd[e];
            }
        }
    }
    __syncthreads();
    if (t == 0) {
        int i = sI, j = sJ, n = sN;
        bt_walk4(sdec, 0, 0, i, j, n, path);
        sN = n;
    }
    __syncthreads();

    const float sc0 = subcoef[0], sc1 = subcoef[1];
    const int n = sN;
    float acc = 0.0f;
    for (int p = t; p < n; p += 256) {
        const unsigned e = path[p];
        const int i = (int)(e >> 16), j = (int)(e & 0xffffu);
        acc += fabsf(pxA[i] - txA[j]) * sc0 + fabsf(pyA[i] - tyA[j]) * sc1;
    }
    #pragma unroll
    for (int o = 32; o > 0; o >>= 1) acc += __shfl_down(acc, o);
    if ((t & 63) == 0) wsum[t >> 6] = acc;
    __syncthreads();
    if (t == 0) atomicAdd(out, (wsum[0] + wsum[1]) + (wsum[2] + wsum[3]));
}

// ------------- Fallback (only if ws too small for everything) ----------------
__global__ __launch_bounds__(256) void dtw_fallback(
    const float* __restrict__ preds, const float* __restrict__ targs,
    const float* __restrict__ subcoef, unsigned* __restrict__ dec,
    float* __restrict__ out)
{
    const int b = blockIdx.x;
    const int t = threadIdx.x;
    const float INF = __builtin_inff();
    __shared__ float px[NN], py[NN];
    __shared__ float txy[2 * MM];
    __shared__ float bbuf[2][256];

    for (int it = 0; it < NN / 256; ++it) {
        const int idx = it * 256 + t;
        const float4 p4 = ((const float4*)preds)[(size_t)b * NN + idx];
        px[idx] = p4.x; py[idx] = p4.y;
        const float4 t4 = ((const float4*)targs)[(size_t)b * MM + idx];
        txy[2 * idx] = t4.x; txy[2 * idx + 1] = t4.y;
    }
    bbuf[0][t] = INF; bbuf[1][t] = INF;
    __syncthreads();

    float pxr[4], pyr[4], Dp[4];
    #pragma unroll
    for (int r = 0; r < 4; ++r) {
        pxr[r] = px[4 * t + r]; pyr[r] = py[4 * t + r]; Dp[r] = INF;
    }
    float dgB = (t == 0) ? 0.0f : INF;
    unsigned packed = 0;
    unsigned* decB = dec + (size_t)b * 65536;
    for (int s = 0; s < MM + 255; ++s) {
        const int j = s - t;
        const float upB = (t == 0) ? INF : bbuf[(s + 1) & 1][t - 1];
        if (j >= 0 && j < MM) {
            const float txj = txy[2 * j], tyj = txy[2 * j + 1];
            float up = upB, dg = dgB;
            unsigned mbits = 0;
            #pragma unroll
            for (int r = 0; r < 4; ++r) {
                const float dx = pxr[r] - txj, dy = pyr[r] - tyj;
                const float c = sqrtf(dx * dx + dy * dy);
                const float lf = Dp[r];
                const unsigned m = (dg <= up && dg <= lf) ? 0u
                                 : ((up <= lf) ? 1u : 2u);
                mbits |= m << (r * 8 + (j & 3) * 2);
                const float Dc = c + fminf(up, fminf(dg, lf));
                dg = lf; up = Dc; Dp[r] = Dc;
            }
            packed |= mbits;
            if ((j & 3) == 3) { decB[(unsigned)t * 256 + (j >> 2)] = packed; packed = 0; }
            bbuf[s & 1][t] = Dp[3];
        }
        dgB = upB;
        __syncthreads();
    }
    __threadfence_block();
    __syncthreads();
    if (t == 0) {
        const float sc0 = subcoef[0], sc1 = subcoef[1];
        int i = NN - 1, jj = MM - 1;
        float loss = 0.0f;
        int ti = i >> 2, tj = jj >> 2;
        unsigned wv = decB[ti * 256 + tj];
        while (true) {
            const int tjl = (tj > 0) ? tj - 1 : 0;
            const int til = (ti > 0) ? ti - 1 : 0;
            const unsigned wl = decB[ti * 256 + tjl];
            const unsigned wu = decB[til * 256 + tj];
            const unsigned wd = decB[til * 256 + tjl];
            bool done = false;
            while (true) {
                loss += fabsf(px[i] - txy[2 * jj]) * sc0
                      + fabsf(py[i] - txy[2 * jj + 1]) * sc1;
                if ((i | jj) == 0) { done = true; break; }
                const unsigned m = (wv >> (((i & 3) * 4 + (jj & 3)) * 2)) & 3u;
                i -= (m != 2u); jj -= (m != 1u);
                if ((i >> 2) != ti || (jj >> 2) != tj) break;
            }
            if (done) break;
            const int nti = i >> 2, ntj = jj >> 2;
            wv = (nti == ti) ? wl : ((ntj == tj) ? wu : wd);
            ti = nti; tj = ntj;
        }
        atomicAdd(out, loss);
    }
}

extern "C" void kernel_launch(void* const* d_in, const int* in_sizes, int n_in,
                              void* d_out, int out_size, void* d_ws, size_t ws_size,
                              hipStream_t stream) {
    const float* preds   = (const float*)d_in[0];
    const float* targs   = (const float*)d_in[1];
    const float* subcoef = (const float*)d_in[2];
    float* out = (float*)d_out;

    if (ws_size >= REQ_WS_NEW) {
        float* wsf = (float*)d_ws;
        init2<<<BATCH, 256, 0, stream>>>(wsf, out);
        for (int d = 0; d < GB + GH - 1; ++d) {          // 11 diagonals
            const int r0 = (d > GH - 1) ? d - (GH - 1) : 0;
            const int r1 = (d < GB - 1) ? d : GB - 1;
            dim3 grid(r1 - r0 + 1, BATCH);
            dtw_panel4<<<grid, 64, 0, stream>>>(preds, targs, wsf, d);
        }
        dtw_bt<<<BATCH, 256, 0, stream>>>(preds, targs, subcoef,
                                          (const unsigned*)d_ws, out);
    } else if (ws_size >= REQ_WS) {
        unsigned* dec = (unsigned*)d_ws;
        init_kernel<<<1, 1, 0, stream>>>(out);
        dtw_fused_legacy<<<BATCH, 256, 0, stream>>>(preds, targs, subcoef, dec, out);
    } else {
        unsigned* dec = (unsigned*)d_ws;
        init_kernel<<<1, 1, 0, stream>>>(out);
        dtw_fallback<<<BATCH, 256, 0, stream>>>(preds, targs, subcoef, dec, out);
    }
}

// Round 12
// 540.712 us; speedup vs baseline: 1.0651x; 1.0651x over previous
//
#include <hip/hip_runtime.h>
#include <math.h>

#define BATCH 32
#define NN 1024
#define MM 1024
#define LPATH (NN + MM - 1)     // 2047

// ---------------- Wavefront-panel geometry ----------------
// 8x8 grid of 128x128 panels per batch. Panel = 1 wave, lane owns 2 rows.
// 15 diagonal launches; boundaries flow through ws between launches.
// SESSION OPTIMUM (R5): measured 540.3 us total (DP ~380, bt ~157), absmax=0.
// Mapped alternatives, all worse: persistent+flags 419us DP (R6), 2-batch
// pairing 539 (R7), fused 1088-step sweep 482-485 (R8/R9), LDS-walk bt 174
// (R10), 4-row panels 399 DP + 174 bt (R11). DP is single-wave dependency/
// issue-bound (~315 cyc/step, VALU 3%, HBM 0.5%) -- not a HW roofline, but
// resistant to DPP/dbuf/sched_barrier/prefetch restructuring at HIP level.
#define PB 128                  // panel rows
#define PQ 128                  // panel cols
#define GB 8                    // bands (rows of panels)
#define GH 8                    // panel columns
#define PAN_WORDS 1536          // 24 sblk x 64 lanes (4 bits/step/lane)
#define BAT_WORDS (GB * GH * PAN_WORDS)               // 98304 words / batch
#define RCPL (9 * 1024)                               // rcol/brow plane floats
#define RC_OFFW ((size_t)BATCH * BAT_WORDS)
#define BR_OFFW (RC_OFFW + (size_t)BATCH * RCPL)
#define WS_WORDS (BR_OFFW + (size_t)BATCH * RCPL)
#define REQ_WS_NEW (WS_WORDS * 4)                     // ~14.3 MB

// Legacy (proven 557us) path requirement
#define DEC_WORDS_PER_BATCH ((NN / 4) * (MM / 4))     // 65536
#define REQ_WS ((size_t)BATCH * DEC_WORDS_PER_BATCH * 4)   // 8 MB

__global__ void init_kernel(float* out) { out[0] = 0.0f; }

// ---- init: INF boundary planes (c=0 / r=0) + out=0 -------------------------
__global__ void init2(float* __restrict__ ws, float* __restrict__ out)
{
    const int b = blockIdx.x, t = threadIdx.x;
    const float INF = __builtin_inff();
    if (b == 0 && t == 0) out[0] = 0.0f;
    float* rc0 = ws + RC_OFFW + (size_t)b * RCPL;     // rcol[b][0][*]
    float* br0 = ws + BR_OFFW + (size_t)b * RCPL;     // brow[b][0][*]
    for (int i = t; i < 1024; i += 256) { rc0[i] = INF; br0[i] = INF; }
}

// DPP wavefront shift-right-1 (dpp_ctrl 0x138): lane l gets lane l-1's value,
// lane 0 keeps its own (old operand) -- exactly __shfl_up(v,1) semantics for
// the lanes we use; VALU-only, no LDS round-trip.
__device__ __forceinline__ float wave_shr1(float v)
{
    return __int_as_float(__builtin_amdgcn_update_dpp(
        __float_as_int(v), __float_as_int(v), 0x138, 0xF, 0xF, false));
}

// ---- Panel DP kernel: launch per grid anti-diagonal -------------------------
// Lane l owns panel-rows 2l, 2l+1. Step s (0..191): lane l computes panel-col
// jq = s - l (predicated to jq in [0,128)). Decisions: 4 bits/step/lane
// (2 cells x 2 bits), word = 8 steps, flushed wave-uniformly -> coalesced
// 256B store; layout dec[b][r*8+c][s>>3][lane].
__global__ __launch_bounds__(64, 1) void dtw_panel(
    const float* __restrict__ preds, const float* __restrict__ targs,
    float* __restrict__ ws, const int diag)
{
    const int b = blockIdx.y;
    const int r0 = (diag > GH - 1) ? diag - (GH - 1) : 0;
    const int r = r0 + blockIdx.x;
    const int c = diag - r;
    const int l = threadIdx.x;
    const float INF = __builtin_inff();

    __shared__ __align__(16) float txP[260], tyP[260];   // padded col streams
    __shared__ __align__(16) float TL[200];              // top row stream
    __shared__ __align__(16) float botL[128];            // bottom row collect

    // pads (reads for inactive jq land here; values unused)
    if (l < 63) { txP[l] = 0.f; tyP[l] = 0.f; }
    txP[191 + l] = 0.f; tyP[191 + l] = 0.f;
    if (l < 6) { txP[255 + l] = 0.f; tyP[255 + l] = 0.f; }
    TL[128 + l] = INF; if (l < 8) TL[192 + l] = INF;

    // stage targ cols [128c .. 128c+127] (basis x,y = features 0,1)
    const float4* tg4 = (const float4*)targs + (size_t)b * MM + c * PQ;
    {
        const float4 a = tg4[l], e = tg4[64 + l];
        txP[63 + l] = a.x;      tyP[63 + l] = a.y;
        txP[63 + 64 + l] = e.x; tyP[63 + 64 + l] = e.y;
    }
    // top boundary row (brow[b][r] holds D of global row 128r-1; r=0 -> INF)
    const float* browR = ws + BR_OFFW + ((size_t)b * 9 + r) * 1024 + c * PQ;
    TL[l] = browR[l]; TL[64 + l] = browR[64 + l];

    // pred rows
    const float4* pp4 = (const float4*)preds + (size_t)b * NN + r * PB;
    const float4 p0 = pp4[2 * l], p1 = pp4[2 * l + 1];
    const float px0 = p0.x, py0 = p0.y, px1 = p1.x, py1 = p1.y;

    // left boundary (rcol[b][c] holds D of global col 128c-1; c=0 -> INF)
    const float* rc = ws + RC_OFFW + ((size_t)b * 9 + c) * 1024 + r * PB;
    float D0 = rc[2 * l], D1 = rc[2 * l + 1];
    const float corner = (c == 0) ? ((r == 0) ? 0.0f : INF) : browR[-1];
    const float dg0init = (l == 0) ? corner : rc[2 * l - 1];

    unsigned* __restrict__ decP = (unsigned*)ws + (size_t)b * BAT_WORDS
                                + (size_t)(r * GH + c) * PAN_WORDS + l;
    __syncthreads();

    // 8-slot register ring for tx/ty, prefetch distance 4 steps
    float txb[8], tyb[8];
    #pragma unroll
    for (int k = 0; k < 4; ++k) { txb[k] = txP[63 + k - l]; tyb[k] = tyP[63 + k - l]; }
    float up0prev = INF;

    for (int it = 0; it < 24; ++it) {
        const int s0 = it * 8;
        const float4 T4a = *(const float4*)&TL[s0];
        const float4 T4b = *(const float4*)&TL[s0 + 4];
        const float Tv[8] = {T4a.x, T4a.y, T4a.z, T4a.w,
                             T4b.x, T4b.y, T4b.z, T4b.w};
        unsigned word = 0;
        #pragma unroll
        for (int k = 0; k < 8; ++k) {
            const int s = s0 + k;
            const int jq = s - l;
            txb[(k + 4) & 7] = txP[63 + jq + 4];
            tyb[(k + 4) & 7] = tyP[63 + jq + 4];
            const float sh = wave_shr1(D1);           // lane l-1's D1, no DS
            const float up0 = (l == 0) ? Tv[k] : sh;
            const float dg0 = (jq == 0) ? dg0init : up0prev;
            const float tx = txb[k], ty = tyb[k];
            // cell (row 2l): math identical to proven kernel (absmax=0)
            const float dx0 = px0 - tx, dy0 = py0 - ty;
            const float c0 = __builtin_amdgcn_sqrtf(dx0 * dx0 + dy0 * dy0);
            const float mn0 = fminf(dg0, fminf(up0, D0));
            const float D0n = c0 + mn0;
            const unsigned m0 = (mn0 == dg0) ? 0u : ((mn0 == up0) ? 1u : 2u);
            // cell (row 2l+1)
            const float dg1 = D0;
            const float dx1 = px1 - tx, dy1 = py1 - ty;
            const float c1 = __builtin_amdgcn_sqrtf(dx1 * dx1 + dy1 * dy1);
            const float mn1 = fminf(dg1, fminf(D0n, D1));
            const float D1n = c1 + mn1;
            const unsigned m1 = (mn1 == dg1) ? 0u : ((mn1 == D0n) ? 1u : 2u);
            word |= (m0 | (m1 << 2)) << (4 * k);
            const bool act = (jq >= 0) && (jq < PQ);
            if (act) { D0 = D0n; D1 = D1n; }
            up0prev = up0;
            if (l == 63 && act) botL[jq] = D1n;   // band bottom row
        }
        decP[it * 64] = word;                     // coalesced 256B store
    }

    // publish right column (D regs frozen at jq=127 by predication)
    float* rcw = ws + RC_OFFW + ((size_t)b * 9 + (c + 1)) * 1024 + r * PB;
    rcw[2 * l] = D0; rcw[2 * l + 1] = D1;
    __syncthreads();
    float* brw = ws + BR_OFFW + ((size_t)b * 9 + (r + 1)) * 1024 + c * PQ;
    brw[l] = botL[l]; brw[64 + l] = botL[64 + l];
}

// ---- Backtrack + loss: 32 blocks x 256 threads ------------------------------
// t0 walks straight out of global memory (dec is L2-resident; word re-fetched
// only when the (lane, step-block, panel) word index changes). Measured best
// among walk variants: global 157us < LDS-staged 174us < 3-prefetch ~265us.
__global__ __launch_bounds__(256, 1) void dtw_bt(
    const float* __restrict__ preds, const float* __restrict__ targs,
    const float* __restrict__ subcoef, const float* __restrict__ ws,
    float* __restrict__ out)
{
    const int b = blockIdx.x, t = threadIdx.x;
    __shared__ float pxA[NN], pyA[NN], txA[MM], tyA[MM];   // 16 KB
    __shared__ unsigned path[2048];                        // 8 KB
    __shared__ int sN;
    __shared__ float wsum[4];

    for (int it = 0; it < 4; ++it) {
        const int idx = it * 256 + t;
        const float4 p4 = ((const float4*)preds)[(size_t)b * NN + idx];
        pxA[idx] = p4.x; pyA[idx] = p4.y;
        const float4 t4 = ((const float4*)targs)[(size_t)b * MM + idx];
        txA[idx] = t4.x; tyA[idx] = t4.y;
    }
    __syncthreads();

    if (t == 0) {
        const unsigned* __restrict__ decB =
            (const unsigned*)ws + (size_t)b * BAT_WORDS;
        int i = NN - 1, j = MM - 1, n = 0;
        int cwidx = -1; unsigned cw = 0;
        while (true) {
            path[n++] = ((unsigned)i << 16) | (unsigned)j;
            if ((i | j) == 0) break;
            const int ll = (i & 127) >> 1;
            const int ss = ll + (j & 127);
            const int widx = (((i >> 7) << 3) + (j >> 7)) * PAN_WORDS
                           + (ss >> 3) * 64 + ll;
            if (widx != cwidx) { cw = decB[widx]; cwidx = widx; }
            const unsigned m = (cw >> ((ss & 7) * 4 + (i & 1) * 2)) & 3u;
            i -= (m != 2u); j -= (m != 1u);
        }
        sN = n;
    }
    __syncthreads();

    const float sc0 = subcoef[0], sc1 = subcoef[1];
    const int n = sN;
    float acc = 0.0f;
    for (int p = t; p < n; p += 256) {
        const unsigned e = path[p];
        const int i = (int)(e >> 16), j = (int)(e & 0xffffu);
        acc += fabsf(pxA[i] - txA[j]) * sc0 + fabsf(pyA[i] - tyA[j]) * sc1;
    }
    #pragma unroll
    for (int o = 32; o > 0; o >>= 1) acc += __shfl_down(acc, o);
    if ((t & 63) == 0) wsum[t >> 6] = acc;
    __syncthreads();
    if (t == 0) atomicAdd(out, (wsum[0] + wsum[1]) + (wsum[2] + wsum[3]));
}

// =================== Legacy proven path (557us, needs 8MB) ===================
__device__ inline void bt_walk4(const unsigned* __restrict__ sdec, int roff,
                                int iLow, int& i, int& j, int& n,
                                unsigned* __restrict__ path)
{
    int ri = i >> 2, jc = j >> 2;
    unsigned w = sdec[(ri - roff) * 256 + jc];
    while (true) {
        const int base = (ri - roff) * 256 + jc;
        const unsigned wl = sdec[(jc > 0)    ? base - 1   : base];
        const unsigned wu = sdec[(ri > roff) ? base - 256 : base];
        const unsigned wd = sdec[(ri > roff && jc > 0) ? base - 257 : base];
        bool done = false, susp = false;
        while (true) {
            path[n++] = ((unsigned)i << 16) | (unsigned)j;
            if ((i | j) == 0) { done = true; break; }
            const unsigned m = (w >> (((i & 3) * 4 + (j & 3)) * 2)) & 3u;
            i -= (m != 2u); j -= (m != 1u);
            if (i < iLow) { susp = true; break; }
            if ((i >> 2) != ri || (j >> 2) != jc) break;
        }
        if (done || susp) break;
        const int nri = i >> 2, njc = j >> 2;
        w = (nri == ri) ? wl : ((njc == jc) ? wu : wd);
        ri = nri; jc = njc;
    }
}

#define RRL 4
#define CCL 4
#define LANES 64
#define NWAVE 4
#define TPBL (MM / 4)
#define NSUP (TPBL + LANES - 1)
#define LAG 72
#define TOTL (NSUP + (NWAVE - 1) * LAG)
#define DEPTH 32

__global__ __launch_bounds__(256, 1) void dtw_fused_legacy(
    const float* __restrict__ preds, const float* __restrict__ targs,
    const float* __restrict__ subcoef, unsigned* __restrict__ dec,
    float* __restrict__ out)
{
    const int b = blockIdx.x, t = threadIdx.x;
    const int l = t & 63, w = t >> 6;
    const float INF = __builtin_inff();

    __shared__ float pxA[NN], pyA[NN], txA[MM], tyA[MM];
    __shared__ float4 ring[NWAVE - 1][DEPTH];
    __shared__ unsigned sdec[128 * 256];
    __shared__ unsigned path[LPATH + 1];
    __shared__ int sI, sJ, sN;
    __shared__ float wsum[NWAVE];

    for (int it = 0; it < NN / 256; ++it) {
        const int idx = it * 256 + t;
        const float4 p4 = ((const float4*)preds)[(size_t)b * NN + idx];
        pxA[idx] = p4.x; pyA[idx] = p4.y;
        const float4 t4 = ((const float4*)targs)[(size_t)b * MM + idx];
        txA[idx] = t4.x; tyA[idx] = t4.y;
    }
    __syncthreads();

    const int i0 = (w << 8) + (l << 2);
    const float4 px4 = ((const float4*)pxA)[i0 >> 2];
    const float4 py4 = ((const float4*)pyA)[i0 >> 2];
    const float px[RRL] = {px4.x, px4.y, px4.z, px4.w};
    const float py[RRL] = {py4.x, py4.y, py4.z, py4.w};
    unsigned* __restrict__ decW =
        dec + (size_t)b * DEC_WORDS_PER_BATCH + ((size_t)w << 14) + (size_t)l;

    float Dp[RRL], Dbot[CCL], bv[CCL];
    #pragma unroll
    for (int r = 0; r < RRL; ++r) Dp[r] = INF;
    #pragma unroll
    for (int c = 0; c < CCL; ++c) { Dbot[c] = INF; bv[c] = INF; }
    float bndRet = (w == 0 && l == 0) ? 0.0f : INF;
    float4 gcur = make_float4(INF, INF, INF, INF);
    float4 tx4 = ((const float4*)txA)[0], ty4 = ((const float4*)tyA)[0];
    const float4* __restrict__ ringR = ring[(w > 0) ? (w - 1) : 0];

    for (int u = 0; u < TOTL; ++u) {
        const int ul = u - LAG * w;
        if (l == 0) {
            const bool gb = (w > 0) && (ul >= 0) && (ul < TPBL);
            bv[0] = gb ? gcur.x : INF; bv[1] = gb ? gcur.y : INF;
            bv[2] = gb ? gcur.z : INF; bv[3] = gb ? gcur.w : INF;
        }
        const bool act = (ul >= l) && (ul < l + TPBL);
        if (act) {
            const float cx[CCL] = {tx4.x, tx4.y, tx4.z, tx4.w};
            const float cy[CCL] = {ty4.x, ty4.y, ty4.z, ty4.w};
            float cost[RRL][CCL];
            #pragma unroll
            for (int c = 0; c < CCL; ++c)
                #pragma unroll
                for (int r = 0; r < RRL; ++r) {
                    const float dx = px[r] - cx[c], dy = py[r] - cy[c];
                    cost[r][c] = __builtin_amdgcn_sqrtf(dx * dx + dy * dy);
                }
            unsigned word = 0;
            #pragma unroll
            for (int c = 0; c < CCL; ++c) {
                float up = bv[c];
                float dg = (c == 0) ? bndRet : bv[c - 1];
                #pragma unroll
                for (int r = 0; r < RRL; ++r) {
                    const float lf = Dp[r];
                    const unsigned m = (dg <= up && dg <= lf) ? 0u
                                     : ((up <= lf) ? 1u : 2u);
                    const float D = cost[r][c] + fminf(dg, fminf(up, lf));
                    word |= m << ((r * 4 + c) * 2);
                    dg = lf; up = D; Dp[r] = D;
                }
                Dbot[c] = up;
            }
            decW[(ul & 255) << 6] = word;
            if (l == LANES - 1 && w < NWAVE - 1)
                ring[w][ul & (DEPTH - 1)] =
                    make_float4(Dbot[0], Dbot[1], Dbot[2], Dbot[3]);
        }
        bndRet = bv[CCL - 1];
        #pragma unroll
        for (int c = 0; c < CCL; ++c) bv[c] = __shfl_up(Dbot[c], 1);
        const int un = ul + 1;
        if (un >= l && un < l + TPBL) {
            const int jn = CCL * (un - l);
            tx4 = ((const float4*)txA)[jn >> 2];
            ty4 = ((const float4*)tyA)[jn >> 2];
        }
        if (w > 0 && un >= 0 && un < TPBL)
            gcur = ringR[(un + 63) & (DEPTH - 1)];
        if ((u & 7) == 7) __syncthreads();
    }

    __threadfence_block();
    __syncthreads();

    const unsigned* __restrict__ decB = dec + (size_t)b * DEC_WORDS_PER_BATCH;
    {
        const uint4* g4 = (const uint4*)(decB + 32768);
        for (int k = t; k < 8192; k += 256) {
            const uint4 v = g4[k];
            const int kb = k << 2;
            const int wv = kb >> 14;
            const int rem = kb & 16383;
            const int q = rem >> 6;
            const int lb = rem & 63;
            const unsigned wd[4] = {v.x, v.y, v.z, v.w};
            #pragma unroll
            for (int e = 0; e < 4; ++e) {
                const int ll = lb + e;
                const int row = (wv << 6) + ll;
                const int jc = (q - ll) & 255;
                sdec[(row << 8) + jc] = wd[e];
            }
        }
    }
    __syncthreads();
    if (t == 0) {
        int i = NN - 1, j = MM - 1, n = 0;
        bt_walk4(sdec, 128, 512, i, j, n, path);
        sI = i; sJ = j; sN = n;
    }
    __syncthreads();
    {
        const uint4* g4 = (const uint4*)decB;
        for (int k = t; k < 8192; k += 256) {
            const uint4 v = g4[k];
            const int kb = k << 2;
            const int wv = kb >> 14;
            const int rem = kb & 16383;
            const int q = rem >> 6;
            const int lb = rem & 63;
            const unsigned wd[4] = {v.x, v.y, v.z, v.w};
            #pragma unroll
            for (int e = 0; e < 4; ++e) {
                const int ll = lb + e;
                const int row = (wv << 6) + ll;
                const int jc = (q - ll) & 255;
                sdec[(row << 8) + jc] = wd[e];
            }
        }
    }
    __syncthreads();
    if (t == 0) {
        int i = sI, j = sJ, n = sN;
        bt_walk4(sdec, 0, 0, i, j, n, path);
        sN = n;
    }
    __syncthreads();

    const float sc0 = subcoef[0], sc1 = subcoef[1];
    const int n = sN;
    float acc = 0.0f;
    for (int p = t; p < n; p += 256) {
        const unsigned e = path[p];
        const int i = (int)(e >> 16), j = (int)(e & 0xffffu);
        acc += fabsf(pxA[i] - txA[j]) * sc0 + fabsf(pyA[i] - tyA[j]) * sc1;
    }
    #pragma unroll
    for (int o = 32; o > 0; o >>= 1) acc += __shfl_down(acc, o);
    if ((t & 63) == 0) wsum[t >> 6] = acc;
    __syncthreads();
    if (t == 0) atomicAdd(out, (wsum[0] + wsum[1]) + (wsum[2] + wsum[3]));
}

// ------------- Fallback (only if ws too small for everything) ----------------
__global__ __launch_bounds__(256) void dtw_fallback(
    const float* __restrict__ preds, const float* __restrict__ targs,
    const float* __restrict__ subcoef, unsigned* __restrict__ dec,
    float* __restrict__ out)
{
    const int b = blockIdx.x;
    const int t = threadIdx.x;
    const float INF = __builtin_inff();
    __shared__ float px[NN], py[NN];
    __shared__ float txy[2 * MM];
    __shared__ float bbuf[2][256];

    for (int it = 0; it < NN / 256; ++it) {
        const int idx = it * 256 + t;
        const float4 p4 = ((const float4*)preds)[(size_t)b * NN + idx];
        px[idx] = p4.x; py[idx] = p4.y;
        const float4 t4 = ((const float4*)targs)[(size_t)b * MM + idx];
        txy[2 * idx] = t4.x; txy[2 * idx + 1] = t4.y;
    }
    bbuf[0][t] = INF; bbuf[1][t] = INF;
    __syncthreads();

    float pxr[4], pyr[4], Dp[4];
    #pragma unroll
    for (int r = 0; r < 4; ++r) {
        pxr[r] = px[4 * t + r]; pyr[r] = py[4 * t + r]; Dp[r] = INF;
    }
    float dgB = (t == 0) ? 0.0f : INF;
    unsigned packed = 0;
    unsigned* decB = dec + (size_t)b * 65536;
    for (int s = 0; s < MM + 255; ++s) {
        const int j = s - t;
        const float upB = (t == 0) ? INF : bbuf[(s + 1) & 1][t - 1];
        if (j >= 0 && j < MM) {
            const float txj = txy[2 * j], tyj = txy[2 * j + 1];
            float up = upB, dg = dgB;
            unsigned mbits = 0;
            #pragma unroll
            for (int r = 0; r < 4; ++r) {
                const float dx = pxr[r] - txj, dy = pyr[r] - tyj;
                const float c = sqrtf(dx * dx + dy * dy);
                const float lf = Dp[r];
                const unsigned m = (dg <= up && dg <= lf) ? 0u
                                 : ((up <= lf) ? 1u : 2u);
                mbits |= m << (r * 8 + (j & 3) * 2);
                const float Dc = c + fminf(up, fminf(dg, lf));
                dg = lf; up = Dc; Dp[r] = Dc;
            }
            packed |= mbits;
            if ((j & 3) == 3) { decB[(unsigned)t * 256 + (j >> 2)] = packed; packed = 0; }
            bbuf[s & 1][t] = Dp[3];
        }
        dgB = upB;
        __syncthreads();
    }
    __threadfence_block();
    __syncthreads();
    if (t == 0) {
        const float sc0 = subcoef[0], sc1 = subcoef[1];
        int i = NN - 1, jj = MM - 1;
        float loss = 0.0f;
        int ti = i >> 2, tj = jj >> 2;
        unsigned wv = decB[ti * 256 + tj];
        while (true) {
            const int tjl = (tj > 0) ? tj - 1 : 0;
            const int til = (ti > 0) ? ti - 1 : 0;
            const unsigned wl = decB[ti * 256 + tjl];
            const unsigned wu = decB[til * 256 + tj];
            const unsigned wd = decB[til * 256 + tjl];
            bool done = false;
            while (true) {
                loss += fabsf(px[i] - txy[2 * jj]) * sc0
                      + fabsf(py[i] - txy[2 * jj + 1]) * sc1;
                if ((i | jj) == 0) { done = true; break; }
                const unsigned m = (wv >> (((i & 3) * 4 + (jj & 3)) * 2)) & 3u;
                i -= (m != 2u); jj -= (m != 1u);
                if ((i >> 2) != ti || (jj >> 2) != tj) break;
            }
            if (done) break;
            const int nti = i >> 2, ntj = jj >> 2;
            wv = (nti == ti) ? wl : ((ntj == tj) ? wu : wd);
            ti = nti; tj = ntj;
        }
        atomicAdd(out, loss);
    }
}

extern "C" void kernel_launch(void* const* d_in, const int* in_sizes, int n_in,
                              void* d_out, int out_size, void* d_ws, size_t ws_size,
                              hipStream_t stream) {
    const float* preds   = (const float*)d_in[0];
    const float* targs   = (const float*)d_in[1];
    const float* subcoef = (const float*)d_in[2];
    float* out = (float*)d_out;

    if (ws_size >= REQ_WS_NEW) {
        float* wsf = (float*)d_ws;
        init2<<<BATCH, 256, 0, stream>>>(wsf, out);
        for (int d = 0; d < GB + GH - 1; ++d) {
            const int r0 = (d > GH - 1) ? d - (GH - 1) : 0;
            const int r1 = (d < GB - 1) ? d : GB - 1;
            dim3 grid(r1 - r0 + 1, BATCH);
            dtw_panel<<<grid, 64, 0, stream>>>(preds, targs, wsf, d);
        }
        dtw_bt<<<BATCH, 256, 0, stream>>>(preds, targs, subcoef,
                                          (const float*)d_ws, out);
    } else if (ws_size >= REQ_WS) {
        unsigned* dec = (unsigned*)d_ws;
        init_kernel<<<1, 1, 0, stream>>>(out);
        dtw_fused_legacy<<<BATCH, 256, 0, stream>>>(preds, targs, subcoef, dec, out);
    } else {
        unsigned* dec = (unsigned*)d_ws;
        init_kernel<<<1, 1, 0, stream>>>(out);
        dtw_fallback<<<BATCH, 256, 0, stream>>>(preds, targs, subcoef, dec, out);
    }
}